// Round 2
// baseline (1030.554 us; speedup 1.0000x reference)
//
#include <hip/hip_runtime.h>
#include <math.h>
#include <stdint.h>

// MultiResEncoding: Instant-NGP 2D multires hash grid. N=2^21, 16 levels,
// F=2, table 2^19 x float2. Level 0 dense 16x16; levels 1..15 hashed.
//
// R2: 4 threads/point, 4 levels/thread, 16 gathers in flight/thread.
// R3/R4: cache-policy hygiene for the latency-bound gather path.
//  - Output stores (268 MB/dispatch) were cycling the 256-MB MALL every
//    dispatch and evicting the 60-MB table set -> FETCH_SIZE 1.26 GB (~17x
//    ideal). Stores now go system-scope write-through non-temporal
//    (sc0 sc1 nt): full-line wave stores, no L2/L3 allocation.
//  - Levels 12-15 (16-MB line footprint, ~128 accesses/line) gathers are
//    nt (evict-first) so they stop evicting levels <=11 (2.5k-200
//    accesses/line) from the 4-MB per-XCD L2.
//  - R4 fix: __builtin_nontemporal_load needs a native ext_vector pointer,
//    not HIP's float2 class -> load as ext_vector float2.

#define TMASK  ((1u << 19) - 1)
#define PRIME2 2654435761u

typedef float vfloat4 __attribute__((ext_vector_type(4)));
typedef float vfloat2 __attribute__((ext_vector_type(2)));

__device__ __forceinline__ void store_bypass(float4* p, vfloat4 v)
{
    // full 128-B lines per wave (64 lanes x 16 B contiguous): write-through
    // costs no extra traffic, and the stream stops thrashing L2/MALL.
    asm volatile("global_store_dwordx4 %0, %1, off sc0 sc1 nt"
                 :: "v"(p), "v"(v) : "memory");
}

__device__ __forceinline__ float2 load_nt8(const char* p)
{
    vfloat2 v = __builtin_nontemporal_load((const vfloat2*)p);
    float2 r; r.x = v.x; r.y = v.y; return r;
}

__global__ __launch_bounds__(256) void mre_kernel(
    const float* __restrict__ cxp, const float* __restrict__ cyp,
    const float2* __restrict__ dense, const float2* __restrict__ hasht,
    float4* __restrict__ out, uint4 wa, uint4 wb)
{
    __shared__ float2 sdense[256];            // 16x16 level-0 grid, 2 KB
    sdense[threadIdx.x] = dense[threadIdx.x];
    __syncthreads();

    unsigned gid = blockIdx.x * 256u + threadIdx.x;
    unsigned n = gid >> 2;
    unsigned j = gid & 3u;                    // levels 4j .. 4j+3

    float x = cxp[n];                         // 4-lane broadcast
    float y = cyp[n];

    // pw[k] packs (r[2k]-1) | (r[2k+1]-1)<<16. Thread j needs pw[2j], pw[2j+1].
    unsigned w0 = j < 2u ? (j == 0u ? wa.x : wa.z) : (j == 2u ? wb.x : wb.z);
    unsigned w1 = j < 2u ? (j == 0u ? wa.y : wa.w) : (j == 2u ? wb.y : wb.w);
    int rm1[4] = { (int)(w0 & 0xffffu), (int)(w0 >> 16),
                   (int)(w1 & 0xffffu), (int)(w1 >> 16) };

    unsigned o00[4], o01[4], o10[4], o11[4];  // byte offsets into hasht
    float wx[4], wy[4];
    unsigned d00 = 0, d01 = 0, d10 = 0, d11 = 0;  // LDS idx for level 0
    const bool lvl0 = (j == 0u);

    #pragma unroll
    for (int k = 0; k < 4; ++k) {
        int r = rm1[k];
        float rf = (float)r;
        float fx = x * rf, fy = y * rf;
        float x0f = floorf(fx), y0f = floorf(fy);
        wx[k] = fx - x0f;  wy[k] = fy - y0f;
        int ix0 = (int)x0f; ix0 = ix0 < 0 ? 0 : (ix0 > r ? r : ix0);
        int iy0 = (int)y0f; iy0 = iy0 < 0 ? 0 : (iy0 > r ? r : iy0);
        int ix1 = ix0 + 1 > r ? r : ix0 + 1;
        int iy1 = iy0 + 1 > r ? r : iy0 + 1;
        if (k == 0) { d00 = ix0 * 16 + iy0; d01 = ix0 * 16 + iy1;
                      d10 = ix1 * 16 + iy0; d11 = ix1 * 16 + iy1; }
        // level l = 4j+k -> hash table l-1; clamp the unused (j=0,k=0) slot
        unsigned ti = j * 4u + (unsigned)k;
        ti = ti == 0u ? 0u : ti - 1u;
        unsigned tb = ti << 22;               // ti * 2^19 entries * 8 B
        unsigned hy0 = (unsigned)iy0 * PRIME2;
        unsigned hy1 = (unsigned)iy1 * PRIME2;
        o00[k] = tb + ((((unsigned)ix0 ^ hy0) & TMASK) << 3);
        o01[k] = tb + ((((unsigned)ix0 ^ hy1) & TMASK) << 3);
        o10[k] = tb + ((((unsigned)ix1 ^ hy0) & TMASK) << 3);
        o11[k] = tb + ((((unsigned)ix1 ^ hy1) & TMASK) << 3);
    }

    const char* hb = (const char*)hasht;
    float2 f00[4], f01[4], f10[4], f11[4];
    if (j == 3u) {
        // levels 12-15: footprint 16 MB, ~128 accesses/line -- can never be
        // L2-resident; nt (evict-first) keeps them from evicting levels <=11.
        #pragma unroll
        for (int k = 0; k < 4; ++k) {
            f00[k] = load_nt8(hb + o00[k]);
            f01[k] = load_nt8(hb + o01[k]);
            f10[k] = load_nt8(hb + o10[k]);
            f11[k] = load_nt8(hb + o11[k]);
        }
    } else {
        // Issue the 12 unconditional gathers (k=1..3) first, then the masked
        // level-4j group, so everything is in flight before the first use.
        #pragma unroll
        for (int k = 1; k < 4; ++k) {
            f00[k] = *(const float2*)(hb + o00[k]);
            f01[k] = *(const float2*)(hb + o01[k]);
            f10[k] = *(const float2*)(hb + o10[k]);
            f11[k] = *(const float2*)(hb + o11[k]);
        }
        if (lvl0) {
            f00[0] = sdense[d00]; f01[0] = sdense[d01];
            f10[0] = sdense[d10]; f11[0] = sdense[d11];
        } else {
            f00[0] = *(const float2*)(hb + o00[0]);
            f01[0] = *(const float2*)(hb + o01[0]);
            f10[0] = *(const float2*)(hb + o10[0]);
            f11[0] = *(const float2*)(hb + o11[0]);
        }
    }

    float2 acc[4];
    #pragma unroll
    for (int k = 0; k < 4; ++k) {
        float omx = 1.0f - wx[k], omy = 1.0f - wy[k];
        float w00 = omx * omy, w01 = omx * wy[k];
        float w10 = wx[k] * omy, w11 = wx[k] * wy[k];
        acc[k].x = f00[k].x * w00 + f01[k].x * w01 + f10[k].x * w10 + f11[k].x * w11;
        acc[k].y = f00[k].y * w00 + f01[k].y * w01 + f10[k].y * w10 + f11[k].y * w11;
    }

    vfloat4 o0 = { acc[0].x, acc[0].y, acc[1].x, acc[1].y };
    vfloat4 o1 = { acc[2].x, acc[2].y, acc[3].x, acc[3].y };
    size_t base = (size_t)n * 8u + 2u * j;
    store_bypass(&out[base], o0);
    store_bypass(&out[base + 1], o1);
}

extern "C" void kernel_launch(void* const* d_in, const int* in_sizes, int n_in,
                              void* d_out, int out_size, void* d_ws, size_t ws_size,
                              hipStream_t stream)
{
    const float*  cx    = (const float*)d_in[0];
    const float*  cy    = (const float*)d_in[1];
    const float2* dense = (const float2*)d_in[2];
    const float2* hasht = (const float2*)d_in[3];
    float4*       out   = (float4*)d_out;
    const int N = in_sizes[0];

    // numpy RES_LEVELS replica (host glibc doubles — verified passing in R2)
    int r[16];
    for (int l = 0; l < 16; ++l) {
        double b = exp((log(2048.0) - log(16.0)) / 15.0);
        r[l] = (int)floor(16.0 * pow(b, (double)l));
    }
    unsigned pw[8];
    for (int k = 0; k < 8; ++k)
        pw[k] = (unsigned)(r[2 * k] - 1) | ((unsigned)(r[2 * k + 1] - 1) << 16);
    uint4 wa = make_uint4(pw[0], pw[1], pw[2], pw[3]);
    uint4 wb = make_uint4(pw[4], pw[5], pw[6], pw[7]);

    long long total = (long long)N * 4;
    int blocks = (int)((total + 255) / 256);
    hipLaunchKernelGGL(mre_kernel, dim3(blocks), dim3(256), 0, stream,
                       cx, cy, dense, hasht, out, wa, wb);
}

// Round 3
// 706.807 us; speedup vs baseline: 1.4580x; 1.4580x over previous
//
#include <hip/hip_runtime.h>
#include <math.h>
#include <stdint.h>

// MultiResEncoding: Instant-NGP 2D multires hash grid. N=2^21, 16 levels,
// F=2, table 2^19 x float2. Level 0 dense 16x16; levels 1..15 hashed.
//
// R5: level->XCD L2 partitioning.
//  - Levels 12-15 are hash-saturated: hot footprint = full 4 MB table each.
//    With every CU gathering all 4 (16 MB) through a 4-MB per-XCD L2, the
//    L2 thrashes -> FETCH 1.26 GB/dispatch (the R2 bottleneck; the R3/R4
//    MALL-thrash theory was disproven: write-bypass doubled WRITE_SIZE and
//    FETCH barely moved).
//  - Kernel 1 (mre_big): levels 12-15 only, level-pure blocks pinned to XCD
//    pairs via bid&7 (2048 persistent blocks, all resident at launch, so the
//    initial round-robin XCD assignment holds). Each XCD's L2 caches exactly
//    ONE 4-MB table -> gathers become L2 hits. Results staged to workspace
//    ws[4][N] float2 with coalesced nontemporal stores.
//  - Kernel 2 (mre_rest): R2 body (plain gathers, nt-builtin stores); the
//    j==3 thread reads ws instead of gathering. Remaining gather footprint
//    per L2 ~4.5 MB (levels 8-11) -> near-resident.
//  - Fallback: if ws_size < 4*N*8 B, launch the proven R2 mono kernel.

#define TMASK  ((1u << 19) - 1)
#define PRIME2 2654435761u

typedef float vfloat4 __attribute__((ext_vector_type(4)));
typedef float vfloat2 __attribute__((ext_vector_type(2)));

// ---------------- Kernel 1: saturated levels 12..15, XCD-pinned ----------
__global__ __launch_bounds__(256, 8) void mre_big(
    const float* __restrict__ cxp, const float* __restrict__ cyp,
    const float2* __restrict__ hasht, vfloat2* __restrict__ ws,
    uint4 rm1v, unsigned N)
{
    unsigned bid = blockIdx.x;
    unsigned xcd = bid & 7u;                       // initial round-robin XCD
    unsigned lv  = xcd >> 1;                       // level = 12 + lv
    unsigned bwl = (bid >> 3) * 2u + (xcd & 1u);   // block-within-level [0,512)
    int r = (int)(lv == 0u ? rm1v.x : lv == 1u ? rm1v.y
                                    : lv == 2u ? rm1v.z : rm1v.w);
    const char* hb = (const char*)hasht + ((size_t)(11u + lv) << 22);
    vfloat2* wbase = ws + (size_t)lv * N;
    float rf = (float)r;

    unsigned stride = 512u * 256u;                 // threads per level
    #pragma unroll 2
    for (unsigned n = bwl * 256u + threadIdx.x; n < N; n += stride) {
        float x = cxp[n], y = cyp[n];
        float fx = x * rf, fy = y * rf;
        float x0f = floorf(fx), y0f = floorf(fy);
        float wx = fx - x0f, wy = fy - y0f;
        int ix0 = (int)x0f; ix0 = ix0 < 0 ? 0 : (ix0 > r ? r : ix0);
        int iy0 = (int)y0f; iy0 = iy0 < 0 ? 0 : (iy0 > r ? r : iy0);
        int ix1 = ix0 + 1 > r ? r : ix0 + 1;
        int iy1 = iy0 + 1 > r ? r : iy0 + 1;
        unsigned hy0 = (unsigned)iy0 * PRIME2;
        unsigned hy1 = (unsigned)iy1 * PRIME2;
        float2 f00 = *(const float2*)(hb + ((((unsigned)ix0 ^ hy0) & TMASK) << 3));
        float2 f01 = *(const float2*)(hb + ((((unsigned)ix0 ^ hy1) & TMASK) << 3));
        float2 f10 = *(const float2*)(hb + ((((unsigned)ix1 ^ hy0) & TMASK) << 3));
        float2 f11 = *(const float2*)(hb + ((((unsigned)ix1 ^ hy1) & TMASK) << 3));
        float omx = 1.0f - wx, omy = 1.0f - wy;
        float w00 = omx * omy, w01 = omx * wy, w10 = wx * omy, w11 = wx * wy;
        vfloat2 acc;
        acc.x = f00.x * w00 + f01.x * w01 + f10.x * w10 + f11.x * w11;
        acc.y = f00.y * w00 + f01.y * w01 + f10.y * w10 + f11.y * w11;
        __builtin_nontemporal_store(acc, wbase + n);   // don't evict the table
    }
}

// ---------------- Kernel 2: levels 0..11 + ws passthrough ----------------
__global__ __launch_bounds__(256) void mre_rest(
    const float* __restrict__ cxp, const float* __restrict__ cyp,
    const float2* __restrict__ dense, const float2* __restrict__ hasht,
    const vfloat2* __restrict__ ws, float4* __restrict__ out,
    uint4 wa, uint4 wb, unsigned N)
{
    __shared__ float2 sdense[256];            // 16x16 level-0 grid, 2 KB
    sdense[threadIdx.x] = dense[threadIdx.x];
    __syncthreads();

    unsigned gid = blockIdx.x * 256u + threadIdx.x;
    unsigned n = gid >> 2;
    unsigned j = gid & 3u;                    // levels 4j .. 4j+3

    float x = cxp[n];                         // 4-lane broadcast
    float y = cyp[n];

    float2 acc[4];
    if (j == 3u) {
        // levels 12-15 precomputed by mre_big
        #pragma unroll
        for (int k = 0; k < 4; ++k) {
            vfloat2 v = ws[(size_t)k * N + n];
            acc[k].x = v.x; acc[k].y = v.y;
        }
    } else {
        unsigned w0 = j == 0u ? wa.x : (j == 1u ? wa.z : wb.x);
        unsigned w1 = j == 0u ? wa.y : (j == 1u ? wa.w : wb.y);
        int rm1[4] = { (int)(w0 & 0xffffu), (int)(w0 >> 16),
                       (int)(w1 & 0xffffu), (int)(w1 >> 16) };

        unsigned o00[4], o01[4], o10[4], o11[4];
        float wx[4], wy[4];
        unsigned d00 = 0, d01 = 0, d10 = 0, d11 = 0;
        const bool lvl0 = (j == 0u);

        #pragma unroll
        for (int k = 0; k < 4; ++k) {
            int r = rm1[k];
            float rf = (float)r;
            float fx = x * rf, fy = y * rf;
            float x0f = floorf(fx), y0f = floorf(fy);
            wx[k] = fx - x0f;  wy[k] = fy - y0f;
            int ix0 = (int)x0f; ix0 = ix0 < 0 ? 0 : (ix0 > r ? r : ix0);
            int iy0 = (int)y0f; iy0 = iy0 < 0 ? 0 : (iy0 > r ? r : iy0);
            int ix1 = ix0 + 1 > r ? r : ix0 + 1;
            int iy1 = iy0 + 1 > r ? r : iy0 + 1;
            if (k == 0) { d00 = ix0 * 16 + iy0; d01 = ix0 * 16 + iy1;
                          d10 = ix1 * 16 + iy0; d11 = ix1 * 16 + iy1; }
            unsigned ti = j * 4u + (unsigned)k;
            ti = ti == 0u ? 0u : ti - 1u;
            unsigned tb = ti << 22;
            unsigned hy0 = (unsigned)iy0 * PRIME2;
            unsigned hy1 = (unsigned)iy1 * PRIME2;
            o00[k] = tb + ((((unsigned)ix0 ^ hy0) & TMASK) << 3);
            o01[k] = tb + ((((unsigned)ix0 ^ hy1) & TMASK) << 3);
            o10[k] = tb + ((((unsigned)ix1 ^ hy0) & TMASK) << 3);
            o11[k] = tb + ((((unsigned)ix1 ^ hy1) & TMASK) << 3);
        }

        const char* hb = (const char*)hasht;
        float2 f00[4], f01[4], f10[4], f11[4];
        #pragma unroll
        for (int k = 1; k < 4; ++k) {
            f00[k] = *(const float2*)(hb + o00[k]);
            f01[k] = *(const float2*)(hb + o01[k]);
            f10[k] = *(const float2*)(hb + o10[k]);
            f11[k] = *(const float2*)(hb + o11[k]);
        }
        if (lvl0) {
            f00[0] = sdense[d00]; f01[0] = sdense[d01];
            f10[0] = sdense[d10]; f11[0] = sdense[d11];
        } else {
            f00[0] = *(const float2*)(hb + o00[0]);
            f01[0] = *(const float2*)(hb + o01[0]);
            f10[0] = *(const float2*)(hb + o10[0]);
            f11[0] = *(const float2*)(hb + o11[0]);
        }

        #pragma unroll
        for (int k = 0; k < 4; ++k) {
            float omx = 1.0f - wx[k], omy = 1.0f - wy[k];
            float w00 = omx * omy, w01 = omx * wy[k];
            float w10 = wx[k] * omy, w11 = wx[k] * wy[k];
            acc[k].x = f00[k].x * w00 + f01[k].x * w01 + f10[k].x * w10 + f11[k].x * w11;
            acc[k].y = f00[k].y * w00 + f01[k].y * w01 + f10[k].y * w10 + f11[k].y * w11;
        }
    }

    vfloat4 o0 = { acc[0].x, acc[0].y, acc[1].x, acc[1].y };
    vfloat4 o1 = { acc[2].x, acc[2].y, acc[3].x, acc[3].y };
    size_t base = (size_t)n * 8u + 2u * j;
    __builtin_nontemporal_store(o0, (vfloat4*)&out[base]);
    __builtin_nontemporal_store(o1, (vfloat4*)&out[base + 1]);
}

// ---------------- Fallback: the proven R2 mono kernel --------------------
__global__ __launch_bounds__(256) void mre_mono(
    const float* __restrict__ cxp, const float* __restrict__ cyp,
    const float2* __restrict__ dense, const float2* __restrict__ hasht,
    float4* __restrict__ out, uint4 wa, uint4 wb)
{
    __shared__ float2 sdense[256];
    sdense[threadIdx.x] = dense[threadIdx.x];
    __syncthreads();

    unsigned gid = blockIdx.x * 256u + threadIdx.x;
    unsigned n = gid >> 2;
    unsigned j = gid & 3u;

    float x = cxp[n];
    float y = cyp[n];

    unsigned w0 = j < 2u ? (j == 0u ? wa.x : wa.z) : (j == 2u ? wb.x : wb.z);
    unsigned w1 = j < 2u ? (j == 0u ? wa.y : wa.w) : (j == 2u ? wb.y : wb.w);
    int rm1[4] = { (int)(w0 & 0xffffu), (int)(w0 >> 16),
                   (int)(w1 & 0xffffu), (int)(w1 >> 16) };

    unsigned o00[4], o01[4], o10[4], o11[4];
    float wx[4], wy[4];
    unsigned d00 = 0, d01 = 0, d10 = 0, d11 = 0;
    const bool lvl0 = (j == 0u);

    #pragma unroll
    for (int k = 0; k < 4; ++k) {
        int r = rm1[k];
        float rf = (float)r;
        float fx = x * rf, fy = y * rf;
        float x0f = floorf(fx), y0f = floorf(fy);
        wx[k] = fx - x0f;  wy[k] = fy - y0f;
        int ix0 = (int)x0f; ix0 = ix0 < 0 ? 0 : (ix0 > r ? r : ix0);
        int iy0 = (int)y0f; iy0 = iy0 < 0 ? 0 : (iy0 > r ? r : iy0);
        int ix1 = ix0 + 1 > r ? r : ix0 + 1;
        int iy1 = iy0 + 1 > r ? r : iy0 + 1;
        if (k == 0) { d00 = ix0 * 16 + iy0; d01 = ix0 * 16 + iy1;
                      d10 = ix1 * 16 + iy0; d11 = ix1 * 16 + iy1; }
        unsigned ti = j * 4u + (unsigned)k;
        ti = ti == 0u ? 0u : ti - 1u;
        unsigned tb = ti << 22;
        unsigned hy0 = (unsigned)iy0 * PRIME2;
        unsigned hy1 = (unsigned)iy1 * PRIME2;
        o00[k] = tb + ((((unsigned)ix0 ^ hy0) & TMASK) << 3);
        o01[k] = tb + ((((unsigned)ix0 ^ hy1) & TMASK) << 3);
        o10[k] = tb + ((((unsigned)ix1 ^ hy0) & TMASK) << 3);
        o11[k] = tb + ((((unsigned)ix1 ^ hy1) & TMASK) << 3);
    }

    const char* hb = (const char*)hasht;
    float2 f00[4], f01[4], f10[4], f11[4];
    #pragma unroll
    for (int k = 1; k < 4; ++k) {
        f00[k] = *(const float2*)(hb + o00[k]);
        f01[k] = *(const float2*)(hb + o01[k]);
        f10[k] = *(const float2*)(hb + o10[k]);
        f11[k] = *(const float2*)(hb + o11[k]);
    }
    if (lvl0) {
        f00[0] = sdense[d00]; f01[0] = sdense[d01];
        f10[0] = sdense[d10]; f11[0] = sdense[d11];
    } else {
        f00[0] = *(const float2*)(hb + o00[0]);
        f01[0] = *(const float2*)(hb + o01[0]);
        f10[0] = *(const float2*)(hb + o10[0]);
        f11[0] = *(const float2*)(hb + o11[0]);
    }

    float2 acc[4];
    #pragma unroll
    for (int k = 0; k < 4; ++k) {
        float omx = 1.0f - wx[k], omy = 1.0f - wy[k];
        float w00 = omx * omy, w01 = omx * wy[k];
        float w10 = wx[k] * omy, w11 = wx[k] * wy[k];
        acc[k].x = f00[k].x * w00 + f01[k].x * w01 + f10[k].x * w10 + f11[k].x * w11;
        acc[k].y = f00[k].y * w00 + f01[k].y * w01 + f10[k].y * w10 + f11[k].y * w11;
    }

    vfloat4 o0 = { acc[0].x, acc[0].y, acc[1].x, acc[1].y };
    vfloat4 o1 = { acc[2].x, acc[2].y, acc[3].x, acc[3].y };
    size_t base = (size_t)n * 8u + 2u * j;
    __builtin_nontemporal_store(o0, (vfloat4*)&out[base]);
    __builtin_nontemporal_store(o1, (vfloat4*)&out[base + 1]);
}

extern "C" void kernel_launch(void* const* d_in, const int* in_sizes, int n_in,
                              void* d_out, int out_size, void* d_ws, size_t ws_size,
                              hipStream_t stream)
{
    const float*  cx    = (const float*)d_in[0];
    const float*  cy    = (const float*)d_in[1];
    const float2* dense = (const float2*)d_in[2];
    const float2* hasht = (const float2*)d_in[3];
    float4*       out   = (float4*)d_out;
    const unsigned N = (unsigned)in_sizes[0];

    // numpy RES_LEVELS replica (host glibc doubles — verified passing in R2)
    int r[16];
    for (int l = 0; l < 16; ++l) {
        double b = exp((log(2048.0) - log(16.0)) / 15.0);
        r[l] = (int)floor(16.0 * pow(b, (double)l));
    }
    unsigned pw[8];
    for (int k = 0; k < 8; ++k)
        pw[k] = (unsigned)(r[2 * k] - 1) | ((unsigned)(r[2 * k + 1] - 1) << 16);
    uint4 wa = make_uint4(pw[0], pw[1], pw[2], pw[3]);
    uint4 wb = make_uint4(pw[4], pw[5], pw[6], pw[7]);

    long long total = (long long)N * 4;
    int blocks = (int)((total + 255) / 256);

    size_t ws_need = (size_t)4 * N * sizeof(float2);   // 67 MB at N=2^21
    if (ws_size >= ws_need && d_ws != nullptr) {
        uint4 rm1v = make_uint4((unsigned)(r[12] - 1), (unsigned)(r[13] - 1),
                                (unsigned)(r[14] - 1), (unsigned)(r[15] - 1));
        vfloat2* ws = (vfloat2*)d_ws;
        hipLaunchKernelGGL(mre_big, dim3(2048), dim3(256), 0, stream,
                           cx, cy, hasht, ws, rm1v, N);
        hipLaunchKernelGGL(mre_rest, dim3(blocks), dim3(256), 0, stream,
                           cx, cy, dense, hasht, (const vfloat2*)ws, out, wa, wb, N);
    } else {
        hipLaunchKernelGGL(mre_mono, dim3(blocks), dim3(256), 0, stream,
                           cx, cy, dense, hasht, out, wa, wb);
    }
}

// Round 4
// 672.988 us; speedup vs baseline: 1.5313x; 1.0503x over previous
//
#include <hip/hip_runtime.h>
#include <math.h>
#include <stdint.h>

// MultiResEncoding: Instant-NGP 2D multires hash grid. N=2^21, 16 levels,
// F=2, table 2^19 x float2. Level 0 dense 16x16; levels 1..15 hashed.
//
// R5: level->XCD L2 partitioning (confirmed: FETCH 1.26 GB -> 79 MB).
//   mre_big: levels 12-15 (hash-saturated, 4 MB hot footprint each) in
//   level-pure blocks pinned to XCD pairs via bid&7; each XCD L2 holds ONE
//   table. Results staged to ws[4][N] float2, coalesced nt stores.
// R6 (this round): rebalance mre_rest. After offload, j==3 threads only did
//   4 ws reads while j=0..2 did 16 gathers (25% dead lanes on every gather
//   instr + divergent branch). Now every thread: 3 gather-levels {3j..3j+2}
//   + 1 ws level {12+j}: 13 full-width loads, no divergence, shorter chain.
//   Per-thread results are non-contiguous in the out row, so stores go
//   through a 9-KB LDS transpose to keep the proven 2x float4-per-thread
//   full-line nt store pattern. ws reads nt (stream-once; don't evict the
//   L2-resident tables).

#define TMASK  ((1u << 19) - 1)
#define PRIME2 2654435761u

typedef float vfloat4 __attribute__((ext_vector_type(4)));
typedef float vfloat2 __attribute__((ext_vector_type(2)));

// ---------------- Kernel 1: saturated levels 12..15, XCD-pinned ----------
__global__ __launch_bounds__(256, 8) void mre_big(
    const float* __restrict__ cxp, const float* __restrict__ cyp,
    const float2* __restrict__ hasht, vfloat2* __restrict__ ws,
    uint4 rm1v, unsigned N)
{
    unsigned bid = blockIdx.x;
    unsigned xcd = bid & 7u;                       // initial round-robin XCD
    unsigned lv  = xcd >> 1;                       // level = 12 + lv
    unsigned bwl = (bid >> 3) * 2u + (xcd & 1u);   // block-within-level [0,512)
    int r = (int)(lv == 0u ? rm1v.x : lv == 1u ? rm1v.y
                                    : lv == 2u ? rm1v.z : rm1v.w);
    const char* hb = (const char*)hasht + ((size_t)(11u + lv) << 22);
    vfloat2* wbase = ws + (size_t)lv * N;
    float rf = (float)r;

    unsigned stride = 512u * 256u;                 // threads per level
    #pragma unroll 2
    for (unsigned n = bwl * 256u + threadIdx.x; n < N; n += stride) {
        float x = cxp[n], y = cyp[n];
        float fx = x * rf, fy = y * rf;
        float x0f = floorf(fx), y0f = floorf(fy);
        float wx = fx - x0f, wy = fy - y0f;
        int ix0 = (int)x0f; ix0 = ix0 < 0 ? 0 : (ix0 > r ? r : ix0);
        int iy0 = (int)y0f; iy0 = iy0 < 0 ? 0 : (iy0 > r ? r : iy0);
        int ix1 = ix0 + 1 > r ? r : ix0 + 1;
        int iy1 = iy0 + 1 > r ? r : iy0 + 1;
        unsigned hy0 = (unsigned)iy0 * PRIME2;
        unsigned hy1 = (unsigned)iy1 * PRIME2;
        float2 f00 = *(const float2*)(hb + ((((unsigned)ix0 ^ hy0) & TMASK) << 3));
        float2 f01 = *(const float2*)(hb + ((((unsigned)ix0 ^ hy1) & TMASK) << 3));
        float2 f10 = *(const float2*)(hb + ((((unsigned)ix1 ^ hy0) & TMASK) << 3));
        float2 f11 = *(const float2*)(hb + ((((unsigned)ix1 ^ hy1) & TMASK) << 3));
        float omx = 1.0f - wx, omy = 1.0f - wy;
        float w00 = omx * omy, w01 = omx * wy, w10 = wx * omy, w11 = wx * wy;
        vfloat2 acc;
        acc.x = f00.x * w00 + f01.x * w01 + f10.x * w10 + f11.x * w11;
        acc.y = f00.y * w00 + f01.y * w01 + f10.y * w10 + f11.y * w11;
        __builtin_nontemporal_store(acc, wbase + n);   // don't evict the table
    }
}

// ---------------- Kernel 2: levels 0..11 + ws merge, balanced ------------
__global__ __launch_bounds__(256) void mre_rest(
    const float* __restrict__ cxp, const float* __restrict__ cyp,
    const float2* __restrict__ dense, const float2* __restrict__ hasht,
    const vfloat2* __restrict__ ws, float4* __restrict__ out,
    uint4 wa, uint4 wb, unsigned N)
{
    __shared__ float2 sdense[256];                 // 16x16 level-0 grid, 2 KB
    __shared__ __align__(16) float sout[64 * 36];  // 64 pts x 32 feats, +4 pad
    sdense[threadIdx.x] = dense[threadIdx.x];
    __syncthreads();

    unsigned gid = blockIdx.x * 256u + threadIdx.x;
    unsigned n  = gid >> 2;
    unsigned j  = gid & 3u;                        // gather levels 3j..3j+2, ws 12+j
    unsigned nl = threadIdx.x >> 2;                // local point 0..63

    float x = cxp[n];                              // 4-lane broadcast
    float y = cyp[n];

    // ws (levels 12-15) stream: issue early, nt so it doesn't evict tables
    vfloat2 wsv = __builtin_nontemporal_load(&ws[(size_t)j * N + n]);

    // resolution-1 words: slot s in word s>>1, half s&1. Thread j needs
    // slots 3j, 3j+1, 3j+2.  word idx per j: {0,1,3,4}, {0,2,3,5}, {1,2,4,5}
    unsigned W0 = wa.x, W1 = wa.y, W2 = wa.z, W3 = wa.w, W4 = wb.x, W5 = wb.y;
    unsigned u0 = j == 0u ? W0 : j == 1u ? W1 : j == 2u ? W3 : W4;
    unsigned u1 = j == 0u ? W0 : j == 1u ? W2 : j == 2u ? W3 : W5;
    unsigned u2 = j == 0u ? W1 : j == 1u ? W2 : j == 2u ? W4 : W5;
    unsigned h0 = (j & 1u) << 4;                   // (3j)&1   * 16
    unsigned h1 = ((j + 1u) & 1u) << 4;            // (3j+1)&1 * 16
    unsigned h2 = (j & 1u) << 4;                   // (3j+2)&1 * 16
    int rm1[3] = { (int)((u0 >> h0) & 0xffffu),
                   (int)((u1 >> h1) & 0xffffu),
                   (int)((u2 >> h2) & 0xffffu) };

    unsigned o00[3], o01[3], o10[3], o11[3];
    float wx[3], wy[3];
    unsigned d00 = 0, d01 = 0, d10 = 0, d11 = 0;

    #pragma unroll
    for (int k = 0; k < 3; ++k) {
        int r = rm1[k];
        float rf = (float)r;
        float fx = x * rf, fy = y * rf;
        float x0f = floorf(fx), y0f = floorf(fy);
        wx[k] = fx - x0f;  wy[k] = fy - y0f;
        int ix0 = (int)x0f; ix0 = ix0 < 0 ? 0 : (ix0 > r ? r : ix0);
        int iy0 = (int)y0f; iy0 = iy0 < 0 ? 0 : (iy0 > r ? r : iy0);
        int ix1 = ix0 + 1 > r ? r : ix0 + 1;
        int iy1 = iy0 + 1 > r ? r : iy0 + 1;
        if (k == 0) { d00 = ix0 * 16 + iy0; d01 = ix0 * 16 + iy1;
                      d10 = ix1 * 16 + iy0; d11 = ix1 * 16 + iy1; }
        unsigned lvl = j * 3u + (unsigned)k;       // level of this slot
        unsigned ti = lvl == 0u ? 0u : lvl - 1u;   // hash table idx (clamped)
        unsigned tb = ti << 22;                    // ti * 2^19 * 8 B
        unsigned hy0 = (unsigned)iy0 * PRIME2;
        unsigned hy1 = (unsigned)iy1 * PRIME2;
        o00[k] = tb + ((((unsigned)ix0 ^ hy0) & TMASK) << 3);
        o01[k] = tb + ((((unsigned)ix0 ^ hy1) & TMASK) << 3);
        o10[k] = tb + ((((unsigned)ix1 ^ hy0) & TMASK) << 3);
        o11[k] = tb + ((((unsigned)ix1 ^ hy1) & TMASK) << 3);
    }

    const char* hb = (const char*)hasht;
    float2 f00[3], f01[3], f10[3], f11[3];
    #pragma unroll
    for (int k = 1; k < 3; ++k) {                  // unconditional: issue first
        f00[k] = *(const float2*)(hb + o00[k]);
        f01[k] = *(const float2*)(hb + o01[k]);
        f10[k] = *(const float2*)(hb + o10[k]);
        f11[k] = *(const float2*)(hb + o11[k]);
    }
    if (j == 0u) {                                 // level 0: dense from LDS
        f00[0] = sdense[d00]; f01[0] = sdense[d01];
        f10[0] = sdense[d10]; f11[0] = sdense[d11];
    } else {
        f00[0] = *(const float2*)(hb + o00[0]);
        f01[0] = *(const float2*)(hb + o01[0]);
        f10[0] = *(const float2*)(hb + o10[0]);
        f11[0] = *(const float2*)(hb + o11[0]);
    }

    // bilerp + stage into LDS row (float offset 2*level within 32, pad to 36)
    float* so = &sout[nl * 36u];
    #pragma unroll
    for (int k = 0; k < 3; ++k) {
        float omx = 1.0f - wx[k], omy = 1.0f - wy[k];
        float w00 = omx * omy, w01 = omx * wy[k];
        float w10 = wx[k] * omy, w11 = wx[k] * wy[k];
        vfloat2 a;
        a.x = f00[k].x * w00 + f01[k].x * w01 + f10[k].x * w10 + f11[k].x * w11;
        a.y = f00[k].y * w00 + f01[k].y * w01 + f10[k].y * w10 + f11[k].y * w11;
        *(vfloat2*)&so[6u * j + 2u * (unsigned)k] = a;
    }
    *(vfloat2*)&so[24u + 2u * j] = wsv;            // levels 12-15 slot

    __syncthreads();

    // read back own quadrant (floats 8j..8j+7) -> proven full-line stores
    const vfloat4* sp = (const vfloat4*)&sout[nl * 36u + 8u * j];
    vfloat4 o0 = sp[0];
    vfloat4 o1 = sp[1];
    size_t base = (size_t)n * 8u + 2u * j;
    __builtin_nontemporal_store(o0, (vfloat4*)&out[base]);
    __builtin_nontemporal_store(o1, (vfloat4*)&out[base + 1]);
}

// ---------------- Fallback: the proven R2 mono kernel --------------------
__global__ __launch_bounds__(256) void mre_mono(
    const float* __restrict__ cxp, const float* __restrict__ cyp,
    const float2* __restrict__ dense, const float2* __restrict__ hasht,
    float4* __restrict__ out, uint4 wa, uint4 wb)
{
    __shared__ float2 sdense[256];
    sdense[threadIdx.x] = dense[threadIdx.x];
    __syncthreads();

    unsigned gid = blockIdx.x * 256u + threadIdx.x;
    unsigned n = gid >> 2;
    unsigned j = gid & 3u;

    float x = cxp[n];
    float y = cyp[n];

    unsigned w0 = j < 2u ? (j == 0u ? wa.x : wa.z) : (j == 2u ? wb.x : wb.z);
    unsigned w1 = j < 2u ? (j == 0u ? wa.y : wa.w) : (j == 2u ? wb.y : wb.w);
    int rm1[4] = { (int)(w0 & 0xffffu), (int)(w0 >> 16),
                   (int)(w1 & 0xffffu), (int)(w1 >> 16) };

    unsigned o00[4], o01[4], o10[4], o11[4];
    float wx[4], wy[4];
    unsigned d00 = 0, d01 = 0, d10 = 0, d11 = 0;
    const bool lvl0 = (j == 0u);

    #pragma unroll
    for (int k = 0; k < 4; ++k) {
        int r = rm1[k];
        float rf = (float)r;
        float fx = x * rf, fy = y * rf;
        float x0f = floorf(fx), y0f = floorf(fy);
        wx[k] = fx - x0f;  wy[k] = fy - y0f;
        int ix0 = (int)x0f; ix0 = ix0 < 0 ? 0 : (ix0 > r ? r : ix0);
        int iy0 = (int)y0f; iy0 = iy0 < 0 ? 0 : (iy0 > r ? r : iy0);
        int ix1 = ix0 + 1 > r ? r : ix0 + 1;
        int iy1 = iy0 + 1 > r ? r : iy0 + 1;
        if (k == 0) { d00 = ix0 * 16 + iy0; d01 = ix0 * 16 + iy1;
                      d10 = ix1 * 16 + iy0; d11 = ix1 * 16 + iy1; }
        unsigned ti = j * 4u + (unsigned)k;
        ti = ti == 0u ? 0u : ti - 1u;
        unsigned tb = ti << 22;
        unsigned hy0 = (unsigned)iy0 * PRIME2;
        unsigned hy1 = (unsigned)iy1 * PRIME2;
        o00[k] = tb + ((((unsigned)ix0 ^ hy0) & TMASK) << 3);
        o01[k] = tb + ((((unsigned)ix0 ^ hy1) & TMASK) << 3);
        o10[k] = tb + ((((unsigned)ix1 ^ hy0) & TMASK) << 3);
        o11[k] = tb + ((((unsigned)ix1 ^ hy1) & TMASK) << 3);
    }

    const char* hb = (const char*)hasht;
    float2 f00[4], f01[4], f10[4], f11[4];
    #pragma unroll
    for (int k = 1; k < 4; ++k) {
        f00[k] = *(const float2*)(hb + o00[k]);
        f01[k] = *(const float2*)(hb + o01[k]);
        f10[k] = *(const float2*)(hb + o10[k]);
        f11[k] = *(const float2*)(hb + o11[k]);
    }
    if (lvl0) {
        f00[0] = sdense[d00]; f01[0] = sdense[d01];
        f10[0] = sdense[d10]; f11[0] = sdense[d11];
    } else {
        f00[0] = *(const float2*)(hb + o00[0]);
        f01[0] = *(const float2*)(hb + o01[0]);
        f10[0] = *(const float2*)(hb + o10[0]);
        f11[0] = *(const float2*)(hb + o11[0]);
    }

    float2 acc[4];
    #pragma unroll
    for (int k = 0; k < 4; ++k) {
        float omx = 1.0f - wx[k], omy = 1.0f - wy[k];
        float w00 = omx * omy, w01 = omx * wy[k];
        float w10 = wx[k] * omy, w11 = wx[k] * wy[k];
        acc[k].x = f00[k].x * w00 + f01[k].x * w01 + f10[k].x * w10 + f11[k].x * w11;
        acc[k].y = f00[k].y * w00 + f01[k].y * w01 + f10[k].y * w10 + f11[k].y * w11;
    }

    vfloat4 o0 = { acc[0].x, acc[0].y, acc[1].x, acc[1].y };
    vfloat4 o1 = { acc[2].x, acc[2].y, acc[3].x, acc[3].y };
    size_t base = (size_t)n * 8u + 2u * j;
    __builtin_nontemporal_store(o0, (vfloat4*)&out[base]);
    __builtin_nontemporal_store(o1, (vfloat4*)&out[base + 1]);
}

extern "C" void kernel_launch(void* const* d_in, const int* in_sizes, int n_in,
                              void* d_out, int out_size, void* d_ws, size_t ws_size,
                              hipStream_t stream)
{
    const float*  cx    = (const float*)d_in[0];
    const float*  cy    = (const float*)d_in[1];
    const float2* dense = (const float2*)d_in[2];
    const float2* hasht = (const float2*)d_in[3];
    float4*       out   = (float4*)d_out;
    const unsigned N = (unsigned)in_sizes[0];

    // numpy RES_LEVELS replica (host glibc doubles — verified passing in R2)
    int r[16];
    for (int l = 0; l < 16; ++l) {
        double b = exp((log(2048.0) - log(16.0)) / 15.0);
        r[l] = (int)floor(16.0 * pow(b, (double)l));
    }
    unsigned pw[8];
    for (int k = 0; k < 8; ++k)
        pw[k] = (unsigned)(r[2 * k] - 1) | ((unsigned)(r[2 * k + 1] - 1) << 16);
    uint4 wa = make_uint4(pw[0], pw[1], pw[2], pw[3]);
    uint4 wb = make_uint4(pw[4], pw[5], pw[6], pw[7]);

    long long total = (long long)N * 4;
    int blocks = (int)((total + 255) / 256);

    size_t ws_need = (size_t)4 * N * sizeof(float2);   // 67 MB at N=2^21
    if (ws_size >= ws_need && d_ws != nullptr) {
        uint4 rm1v = make_uint4((unsigned)(r[12] - 1), (unsigned)(r[13] - 1),
                                (unsigned)(r[14] - 1), (unsigned)(r[15] - 1));
        vfloat2* ws = (vfloat2*)d_ws;
        hipLaunchKernelGGL(mre_big, dim3(2048), dim3(256), 0, stream,
                           cx, cy, hasht, ws, rm1v, N);
        hipLaunchKernelGGL(mre_rest, dim3(blocks), dim3(256), 0, stream,
                           cx, cy, dense, hasht, (const vfloat2*)ws, out, wa, wb, N);
    } else {
        hipLaunchKernelGGL(mre_mono, dim3(blocks), dim3(256), 0, stream,
                           cx, cy, dense, hasht, out, wa, wb);
    }
}

// Round 5
// 616.355 us; speedup vs baseline: 1.6720x; 1.0919x over previous
//
#include <hip/hip_runtime.h>
#include <math.h>
#include <stdint.h>

// MultiResEncoding: Instant-NGP 2D multires hash grid. N=2^21, 16 levels,
// F=2, table 2^19 x float2. Level 0 dense 16x16; levels 1..15 hashed.
//
// R5: level->XCD L2 partitioning (confirmed: FETCH 1.26 GB -> 64 MB).
//   mre_big: levels 12-15 (hash-saturated, full-table hot footprint) in
//   level-pure blocks pinned to XCD pairs via bid&7. Results staged to
//   ws[4][N] float2, coalesced nt stores.
// R6: balanced mre_rest: every thread 3 gather-levels {3j..3j+2} + 1 ws
//   level {12+j}; LDS transpose keeps the full-line float4 store pattern.
// R7 (this round): x-pair gather merge. PRIME[0]==1 => h(ix)=ix^(iy*P2),
//   so for even ix0 the corners (ix0,ix0+1) hash to {h,h^1} = one aligned
//   16-B table pair -> ONE dwordx4 load replaces two 8-B gathers (halves
//   both TA lane-requests and L1-fill traffic for that pair). Clamped edge
//   (ix1==ix0) also merges. ~50% of pairs merge => per-level requests 4->3.
//   Rationale: rest runs at 0.65 lane-req/cy/CU, big at 0.44 with L2-fill
//   BW near the per-XCD share -- request/fill-rate bound, so cut requests.

#define TMASK  ((1u << 19) - 1)
#define PRIME2 2654435761u

typedef float vfloat4 __attribute__((ext_vector_type(4)));
typedef float vfloat2 __attribute__((ext_vector_type(2)));

// Load table entries h0,h1 (indices, 8 B each) from table base tp.
// If h1 in {h0, h0^1} (even-ix0 pair or clamped edge), one 16-B load.
__device__ __forceinline__ void pair_gather(const char* tp, unsigned h0,
                                            unsigned h1, float2& a, float2& b)
{
    if (((h0 ^ h1) | 1u) == 1u) {
        vfloat4 q = *(const vfloat4*)(tp + ((h0 & ~1u) << 3));
        a.x = (h0 & 1u) ? q.z : q.x;  a.y = (h0 & 1u) ? q.w : q.y;
        b.x = (h1 & 1u) ? q.z : q.x;  b.y = (h1 & 1u) ? q.w : q.y;
    } else {
        a = *(const float2*)(tp + ((size_t)h0 << 3));
        b = *(const float2*)(tp + ((size_t)h1 << 3));
    }
}

// ---------------- Kernel 1: saturated levels 12..15, XCD-pinned ----------
__global__ __launch_bounds__(256, 8) void mre_big(
    const float* __restrict__ cxp, const float* __restrict__ cyp,
    const float2* __restrict__ hasht, vfloat2* __restrict__ ws,
    uint4 rm1v, unsigned N)
{
    unsigned bid = blockIdx.x;
    unsigned xcd = bid & 7u;                       // initial round-robin XCD
    unsigned lv  = xcd >> 1;                       // level = 12 + lv
    unsigned bwl = (bid >> 3) * 2u + (xcd & 1u);   // block-within-level [0,512)
    int r = (int)(lv == 0u ? rm1v.x : lv == 1u ? rm1v.y
                                    : lv == 2u ? rm1v.z : rm1v.w);
    const char* hb = (const char*)hasht + ((size_t)(11u + lv) << 22);
    vfloat2* wbase = ws + (size_t)lv * N;
    float rf = (float)r;

    unsigned stride = 512u * 256u;                 // threads per level
    #pragma unroll 2
    for (unsigned n = bwl * 256u + threadIdx.x; n < N; n += stride) {
        float x = cxp[n], y = cyp[n];
        float fx = x * rf, fy = y * rf;
        float x0f = floorf(fx), y0f = floorf(fy);
        float wx = fx - x0f, wy = fy - y0f;
        int ix0 = (int)x0f; ix0 = ix0 < 0 ? 0 : (ix0 > r ? r : ix0);
        int iy0 = (int)y0f; iy0 = iy0 < 0 ? 0 : (iy0 > r ? r : iy0);
        int ix1 = ix0 + 1 > r ? r : ix0 + 1;
        int iy1 = iy0 + 1 > r ? r : iy0 + 1;
        unsigned hy0 = (unsigned)iy0 * PRIME2;
        unsigned hy1 = (unsigned)iy1 * PRIME2;
        unsigned h00 = ((unsigned)ix0 ^ hy0) & TMASK;
        unsigned h10 = ((unsigned)ix1 ^ hy0) & TMASK;
        unsigned h01 = ((unsigned)ix0 ^ hy1) & TMASK;
        unsigned h11 = ((unsigned)ix1 ^ hy1) & TMASK;
        float2 f00, f01, f10, f11;
        pair_gather(hb, h00, h10, f00, f10);
        pair_gather(hb, h01, h11, f01, f11);
        float omx = 1.0f - wx, omy = 1.0f - wy;
        float w00 = omx * omy, w01 = omx * wy, w10 = wx * omy, w11 = wx * wy;
        vfloat2 acc;
        acc.x = f00.x * w00 + f01.x * w01 + f10.x * w10 + f11.x * w11;
        acc.y = f00.y * w00 + f01.y * w01 + f10.y * w10 + f11.y * w11;
        __builtin_nontemporal_store(acc, wbase + n);   // don't evict the table
    }
}

// ---------------- Kernel 2: levels 0..11 + ws merge, balanced ------------
__global__ __launch_bounds__(256) void mre_rest(
    const float* __restrict__ cxp, const float* __restrict__ cyp,
    const float2* __restrict__ dense, const float2* __restrict__ hasht,
    const vfloat2* __restrict__ ws, float4* __restrict__ out,
    uint4 wa, uint4 wb, unsigned N)
{
    __shared__ float2 sdense[256];                 // 16x16 level-0 grid, 2 KB
    __shared__ __align__(16) float sout[64 * 36];  // 64 pts x 32 feats, +4 pad
    sdense[threadIdx.x] = dense[threadIdx.x];
    __syncthreads();

    unsigned gid = blockIdx.x * 256u + threadIdx.x;
    unsigned n  = gid >> 2;
    unsigned j  = gid & 3u;                        // gather levels 3j..3j+2, ws 12+j
    unsigned nl = threadIdx.x >> 2;                // local point 0..63

    float x = cxp[n];                              // 4-lane broadcast
    float y = cyp[n];

    // ws (levels 12-15) stream: issue early, nt so it doesn't evict tables
    vfloat2 wsv = __builtin_nontemporal_load(&ws[(size_t)j * N + n]);

    // resolution-1 words: slot s in word s>>1, half s&1. Thread j needs
    // slots 3j, 3j+1, 3j+2.  word idx per j: {0,1,3,4}, {0,2,3,5}, {1,2,4,5}
    unsigned W0 = wa.x, W1 = wa.y, W2 = wa.z, W3 = wa.w, W4 = wb.x, W5 = wb.y;
    unsigned u0 = j == 0u ? W0 : j == 1u ? W1 : j == 2u ? W3 : W4;
    unsigned u1 = j == 0u ? W0 : j == 1u ? W2 : j == 2u ? W3 : W5;
    unsigned u2 = j == 0u ? W1 : j == 1u ? W2 : j == 2u ? W4 : W5;
    unsigned h0 = (j & 1u) << 4;                   // (3j)&1   * 16
    unsigned h1 = ((j + 1u) & 1u) << 4;            // (3j+1)&1 * 16
    unsigned h2 = (j & 1u) << 4;                   // (3j+2)&1 * 16
    int rm1[3] = { (int)((u0 >> h0) & 0xffffu),
                   (int)((u1 >> h1) & 0xffffu),
                   (int)((u2 >> h2) & 0xffffu) };

    unsigned h00[3], h01[3], h10[3], h11[3];       // hash entry indices
    unsigned tbo[3];                               // table byte offsets
    float wx[3], wy[3];
    unsigned d00 = 0, d01 = 0, d10 = 0, d11 = 0;

    #pragma unroll
    for (int k = 0; k < 3; ++k) {
        int r = rm1[k];
        float rf = (float)r;
        float fx = x * rf, fy = y * rf;
        float x0f = floorf(fx), y0f = floorf(fy);
        wx[k] = fx - x0f;  wy[k] = fy - y0f;
        int ix0 = (int)x0f; ix0 = ix0 < 0 ? 0 : (ix0 > r ? r : ix0);
        int iy0 = (int)y0f; iy0 = iy0 < 0 ? 0 : (iy0 > r ? r : iy0);
        int ix1 = ix0 + 1 > r ? r : ix0 + 1;
        int iy1 = iy0 + 1 > r ? r : iy0 + 1;
        if (k == 0) { d00 = ix0 * 16 + iy0; d01 = ix0 * 16 + iy1;
                      d10 = ix1 * 16 + iy0; d11 = ix1 * 16 + iy1; }
        unsigned lvl = j * 3u + (unsigned)k;       // level of this slot
        unsigned ti = lvl == 0u ? 0u : lvl - 1u;   // hash table idx (clamped)
        tbo[k] = ti << 22;                         // ti * 2^19 * 8 B
        unsigned hy0 = (unsigned)iy0 * PRIME2;
        unsigned hy1 = (unsigned)iy1 * PRIME2;
        h00[k] = ((unsigned)ix0 ^ hy0) & TMASK;
        h01[k] = ((unsigned)ix0 ^ hy1) & TMASK;
        h10[k] = ((unsigned)ix1 ^ hy0) & TMASK;
        h11[k] = ((unsigned)ix1 ^ hy1) & TMASK;
    }

    const char* hb = (const char*)hasht;
    float2 f00[3], f01[3], f10[3], f11[3];
    #pragma unroll
    for (int k = 1; k < 3; ++k) {                  // unconditional: issue first
        const char* tp = hb + tbo[k];
        pair_gather(tp, h00[k], h10[k], f00[k], f10[k]);
        pair_gather(tp, h01[k], h11[k], f01[k], f11[k]);
    }
    if (j == 0u) {                                 // level 0: dense from LDS
        f00[0] = sdense[d00]; f01[0] = sdense[d01];
        f10[0] = sdense[d10]; f11[0] = sdense[d11];
    } else {
        const char* tp = hb + tbo[0];
        pair_gather(tp, h00[0], h10[0], f00[0], f10[0]);
        pair_gather(tp, h01[0], h11[0], f01[0], f11[0]);
    }

    // bilerp + stage into LDS row (float offset 2*level within 32, pad to 36)
    float* so = &sout[nl * 36u];
    #pragma unroll
    for (int k = 0; k < 3; ++k) {
        float omx = 1.0f - wx[k], omy = 1.0f - wy[k];
        float w00 = omx * omy, w01 = omx * wy[k];
        float w10 = wx[k] * omy, w11 = wx[k] * wy[k];
        vfloat2 a;
        a.x = f00[k].x * w00 + f01[k].x * w01 + f10[k].x * w10 + f11[k].x * w11;
        a.y = f00[k].y * w00 + f01[k].y * w01 + f10[k].y * w10 + f11[k].y * w11;
        *(vfloat2*)&so[6u * j + 2u * (unsigned)k] = a;
    }
    *(vfloat2*)&so[24u + 2u * j] = wsv;            // levels 12-15 slot

    __syncthreads();

    // read back own quadrant (floats 8j..8j+7) -> proven full-line stores
    const vfloat4* sp = (const vfloat4*)&sout[nl * 36u + 8u * j];
    vfloat4 o0 = sp[0];
    vfloat4 o1 = sp[1];
    size_t base = (size_t)n * 8u + 2u * j;
    __builtin_nontemporal_store(o0, (vfloat4*)&out[base]);
    __builtin_nontemporal_store(o1, (vfloat4*)&out[base + 1]);
}

// ---------------- Fallback: the proven R2 mono kernel --------------------
__global__ __launch_bounds__(256) void mre_mono(
    const float* __restrict__ cxp, const float* __restrict__ cyp,
    const float2* __restrict__ dense, const float2* __restrict__ hasht,
    float4* __restrict__ out, uint4 wa, uint4 wb)
{
    __shared__ float2 sdense[256];
    sdense[threadIdx.x] = dense[threadIdx.x];
    __syncthreads();

    unsigned gid = blockIdx.x * 256u + threadIdx.x;
    unsigned n = gid >> 2;
    unsigned j = gid & 3u;

    float x = cxp[n];
    float y = cyp[n];

    unsigned w0 = j < 2u ? (j == 0u ? wa.x : wa.z) : (j == 2u ? wb.x : wb.z);
    unsigned w1 = j < 2u ? (j == 0u ? wa.y : wa.w) : (j == 2u ? wb.y : wb.w);
    int rm1[4] = { (int)(w0 & 0xffffu), (int)(w0 >> 16),
                   (int)(w1 & 0xffffu), (int)(w1 >> 16) };

    unsigned o00[4], o01[4], o10[4], o11[4];
    float wx[4], wy[4];
    unsigned d00 = 0, d01 = 0, d10 = 0, d11 = 0;
    const bool lvl0 = (j == 0u);

    #pragma unroll
    for (int k = 0; k < 4; ++k) {
        int r = rm1[k];
        float rf = (float)r;
        float fx = x * rf, fy = y * rf;
        float x0f = floorf(fx), y0f = floorf(fy);
        wx[k] = fx - x0f;  wy[k] = fy - y0f;
        int ix0 = (int)x0f; ix0 = ix0 < 0 ? 0 : (ix0 > r ? r : ix0);
        int iy0 = (int)y0f; iy0 = iy0 < 0 ? 0 : (iy0 > r ? r : iy0);
        int ix1 = ix0 + 1 > r ? r : ix0 + 1;
        int iy1 = iy0 + 1 > r ? r : iy0 + 1;
        if (k == 0) { d00 = ix0 * 16 + iy0; d01 = ix0 * 16 + iy1;
                      d10 = ix1 * 16 + iy0; d11 = ix1 * 16 + iy1; }
        unsigned ti = j * 4u + (unsigned)k;
        ti = ti == 0u ? 0u : ti - 1u;
        unsigned tb = ti << 22;
        unsigned hy0 = (unsigned)iy0 * PRIME2;
        unsigned hy1 = (unsigned)iy1 * PRIME2;
        o00[k] = tb + ((((unsigned)ix0 ^ hy0) & TMASK) << 3);
        o01[k] = tb + ((((unsigned)ix0 ^ hy1) & TMASK) << 3);
        o10[k] = tb + ((((unsigned)ix1 ^ hy0) & TMASK) << 3);
        o11[k] = tb + ((((unsigned)ix1 ^ hy1) & TMASK) << 3);
    }

    const char* hb = (const char*)hasht;
    float2 f00[4], f01[4], f10[4], f11[4];
    #pragma unroll
    for (int k = 1; k < 4; ++k) {
        f00[k] = *(const float2*)(hb + o00[k]);
        f01[k] = *(const float2*)(hb + o01[k]);
        f10[k] = *(const float2*)(hb + o10[k]);
        f11[k] = *(const float2*)(hb + o11[k]);
    }
    if (lvl0) {
        f00[0] = sdense[d00]; f01[0] = sdense[d01];
        f10[0] = sdense[d10]; f11[0] = sdense[d11];
    } else {
        f00[0] = *(const float2*)(hb + o00[0]);
        f01[0] = *(const float2*)(hb + o01[0]);
        f10[0] = *(const float2*)(hb + o10[0]);
        f11[0] = *(const float2*)(hb + o11[0]);
    }

    float2 acc[4];
    #pragma unroll
    for (int k = 0; k < 4; ++k) {
        float omx = 1.0f - wx[k], omy = 1.0f - wy[k];
        float w00 = omx * omy, w01 = omx * wy[k];
        float w10 = wx[k] * omy, w11 = wx[k] * wy[k];
        acc[k].x = f00[k].x * w00 + f01[k].x * w01 + f10[k].x * w10 + f11[k].x * w11;
        acc[k].y = f00[k].y * w00 + f01[k].y * w01 + f10[k].y * w10 + f11[k].y * w11;
    }

    vfloat4 o0 = { acc[0].x, acc[0].y, acc[1].x, acc[1].y };
    vfloat4 o1 = { acc[2].x, acc[2].y, acc[3].x, acc[3].y };
    size_t base = (size_t)n * 8u + 2u * j;
    __builtin_nontemporal_store(o0, (vfloat4*)&out[base]);
    __builtin_nontemporal_store(o1, (vfloat4*)&out[base + 1]);
}

extern "C" void kernel_launch(void* const* d_in, const int* in_sizes, int n_in,
                              void* d_out, int out_size, void* d_ws, size_t ws_size,
                              hipStream_t stream)
{
    const float*  cx    = (const float*)d_in[0];
    const float*  cy    = (const float*)d_in[1];
    const float2* dense = (const float2*)d_in[2];
    const float2* hasht = (const float2*)d_in[3];
    float4*       out   = (float4*)d_out;
    const unsigned N = (unsigned)in_sizes[0];

    // numpy RES_LEVELS replica (host glibc doubles — verified passing in R2)
    int r[16];
    for (int l = 0; l < 16; ++l) {
        double b = exp((log(2048.0) - log(16.0)) / 15.0);
        r[l] = (int)floor(16.0 * pow(b, (double)l));
    }
    unsigned pw[8];
    for (int k = 0; k < 8; ++k)
        pw[k] = (unsigned)(r[2 * k] - 1) | ((unsigned)(r[2 * k + 1] - 1) << 16);
    uint4 wa = make_uint4(pw[0], pw[1], pw[2], pw[3]);
    uint4 wb = make_uint4(pw[4], pw[5], pw[6], pw[7]);

    long long total = (long long)N * 4;
    int blocks = (int)((total + 255) / 256);

    size_t ws_need = (size_t)4 * N * sizeof(float2);   // 67 MB at N=2^21
    if (ws_size >= ws_need && d_ws != nullptr) {
        uint4 rm1v = make_uint4((unsigned)(r[12] - 1), (unsigned)(r[13] - 1),
                                (unsigned)(r[14] - 1), (unsigned)(r[15] - 1));
        vfloat2* ws = (vfloat2*)d_ws;
        hipLaunchKernelGGL(mre_big, dim3(2048), dim3(256), 0, stream,
                           cx, cy, hasht, ws, rm1v, N);
        hipLaunchKernelGGL(mre_rest, dim3(blocks), dim3(256), 0, stream,
                           cx, cy, dense, hasht, (const vfloat2*)ws, out, wa, wb, N);
    } else {
        hipLaunchKernelGGL(mre_mono, dim3(blocks), dim3(256), 0, stream,
                           cx, cy, dense, hasht, out, wa, wb);
    }
}